// Round 20
// baseline (275.737 us; speedup 1.0000x reference)
//
#include <hip/hip_runtime.h>

// WKV7 (RWKV-7) forward scan. T=2048, H=64, D=64.
// R20 = R19 + inline exp (pre-pass kernel REMOVED). exp applied to nx1.e
// one body before consumption (off the carried chain, trans pipe).
// R19 structure (best verified, 243us bench): 1024 blocks x 64 thr, width-16
// 2-op global_load_lds staging, 8-slot 2KB ring, 3-deep reg buffers, dual
// interleaved DPP reduce (s_nop 1 entry hazard), batched y-store (1 scatter
// store per 8 steps), counted vmcnt(10)/lgkmcnt(6).
// Model (fitted R5-R19): step time ~ per-CU mem-op service wall:
// 4 waves x (6 ds_read + 2 DMA + 1/8 store) ~= 33 wave-ops x ~9-12 cyc.

typedef float f32x4 __attribute__((ext_vector_type(4)));

constexpr int T_LEN = 2048;
constexpr int DD    = 64;
constexpr int HD    = 64 * 64;   // 4096

#define AS1 __attribute__((address_space(1)))
#define AS3 __attribute__((address_space(3)))

struct Buf { f32x4 r, e, k, a, b; float vv; };

template<int CTRL>
__device__ __forceinline__ float dpp_add(float x) {
  int y = __builtin_amdgcn_update_dpp(0, __float_as_int(x), CTRL, 0xf, 0xf, true);
  return x + __int_as_float(y);
}

// Serial 16-lane reduce (prologue only).
__device__ __forceinline__ float row16_reduce(float x) {
  x = dpp_add<0xB1>(x);    // quad_perm [1,0,3,2]
  x = dpp_add<0x4E>(x);    // quad_perm [2,3,0,1]
  x = dpp_add<0x141>(x);   // row_half_mirror
  x = dpp_add<0x140>(x);   // row_mirror
  return x;
}

// Two interleaved row-of-16 reductions; s_nop 1 covers the entry
// VALU-write -> DPP-read hazard (R8 lesson).
__device__ __forceinline__ void duo_reduce(float& a, float& b) {
  float t0, t1;
  asm volatile(
    "s_nop 1\n\t"
    "v_mov_b32_dpp %2, %0 quad_perm:[1,0,3,2] row_mask:0xf bank_mask:0xf\n\t"
    "v_mov_b32_dpp %3, %1 quad_perm:[1,0,3,2] row_mask:0xf bank_mask:0xf\n\t"
    "s_nop 0\n\t"
    "v_add_f32 %0, %0, %2\n\t"
    "v_add_f32 %1, %1, %3\n\t"
    "s_nop 0\n\t"
    "v_mov_b32_dpp %2, %0 quad_perm:[2,3,0,1] row_mask:0xf bank_mask:0xf\n\t"
    "v_mov_b32_dpp %3, %1 quad_perm:[2,3,0,1] row_mask:0xf bank_mask:0xf\n\t"
    "s_nop 0\n\t"
    "v_add_f32 %0, %0, %2\n\t"
    "v_add_f32 %1, %1, %3\n\t"
    "s_nop 0\n\t"
    "v_mov_b32_dpp %2, %0 row_half_mirror row_mask:0xf bank_mask:0xf\n\t"
    "v_mov_b32_dpp %3, %1 row_half_mirror row_mask:0xf bank_mask:0xf\n\t"
    "s_nop 0\n\t"
    "v_add_f32 %0, %0, %2\n\t"
    "v_add_f32 %1, %1, %3\n\t"
    "s_nop 0\n\t"
    "v_mov_b32_dpp %2, %0 row_mirror row_mask:0xf bank_mask:0xf\n\t"
    "v_mov_b32_dpp %3, %1 row_mirror row_mask:0xf bank_mask:0xf\n\t"
    "s_nop 0\n\t"
    "v_add_f32 %0, %0, %2\n\t"
    "v_add_f32 %1, %1, %3"
    : "+v"(a), "+v"(b), "=&v"(t0), "=&v"(t1));
}

__device__ __forceinline__ float dot4(const f32x4& x, const f32x4& y) {
  return fmaf(x[3], y[3], fmaf(x[2], y[2], fmaf(x[1], y[1], x[0] * y[0])));
}

__device__ __forceinline__ void gload_lds16(const float* g, const float* l) {
  __builtin_amdgcn_global_load_lds((const AS1 unsigned*)g, (AS3 unsigned*)l, 16, 0, 0);
}

__global__ __launch_bounds__(64, 1)
void wkv7_scan(const float* __restrict__ R, const float* __restrict__ W,
               const float* __restrict__ K, const float* __restrict__ V,
               const float* __restrict__ A, const float* __restrict__ B,
               const float* __restrict__ S0, float* __restrict__ X,
               float* __restrict__ SOUT)
{
  // 8 slots x 512 floats (2KB: R|W|K|A | B|V|pad) = 16 KB
  __shared__ float smem[4096];

  const int blk = blockIdx.x;          // 0..1023
  const int xcd = blk & 7;
  const int m   = blk >> 3;            // 0..127
  const int h   = xcd * 8 + (m & 7);   // head 0..63
  const int br  = m >> 3;              // row block 0..15

  const int lane = threadIdx.x;        // 0..63
  const int cg   = lane & 15;          // cols [cg*4, cg*4+4)
  const int rl   = lane >> 4;          // local row 0..3
  const int row  = br * 4 + rl;        // 0..63
  const int c0   = cg * 4;

  // Staging sources (width-16 lane grouping): op1 carries R|W|K|A,
  // op2 carries B|V (g1>=1 dups V into pad -- harmless).
  const int g1   = lane >> 4;          // source-array group 0..3
  const int sub16 = lane & 15;         // 16B chunk within the 256B array
  const float* base1 = (g1 == 0) ? R : (g1 == 1) ? W : (g1 == 2) ? K : A;
  const float* base2 = (g1 == 0) ? B : V;
  const float* p1 = base1 + h * DD + sub16 * 4;
  const float* p2 = base2 + h * DD + sub16 * 4;

  const unsigned lb  = (unsigned)(uintptr_t)(AS3 float*)&smem[0];
  const unsigned vab = lb + (unsigned)(cg * 16);   // vector-read base
  const unsigned vvb = lb + (unsigned)(row * 4);   // v-read base (+1280 imm)

  // y batched store: lane cg<8 stores step (t0+cg) of its row.
  const int ybo = (cg * HD + h * DD + row) * 4;

  f32x4 s;
  {
    const f32x4* sp = (const f32x4*)(S0 + (size_t)h * DD * DD + row * DD + c0);
    s = *sp;
  }

  auto stage = [&](int tt, int slot) {
    const size_t o = (size_t)tt * HD;
    const float* l = &smem[slot * 512];
    gload_lds16(p1 + o, l);          // R|W|K|A -> slot[0..1024)B
    gload_lds16(p2 + o, l + 256);    // B|V|pad -> slot[1024..2048)B
  };

  auto lds_read = [&](Buf& d, int slot) {
    unsigned va = vab + (unsigned)(slot * 2048);
    unsigned vv = vvb + (unsigned)(slot * 2048);
    asm volatile(
      "ds_read_b128 %0, %6\n\t"
      "ds_read_b128 %1, %6 offset:256\n\t"
      "ds_read_b128 %2, %6 offset:512\n\t"
      "ds_read_b128 %3, %6 offset:768\n\t"
      "ds_read_b128 %4, %6 offset:1024\n\t"
      "ds_read_b32  %5, %7 offset:1280"
      : "=&v"(d.r), "=&v"(d.e), "=&v"(d.k), "=&v"(d.a), "=&v"(d.b), "=&v"(d.vv)
      : "v"(va), "v"(vv) : "memory");
  };

  auto wait_nx1 = [&](Buf& d) {
    asm volatile("s_waitcnt lgkmcnt(6)"
                 : "+v"(d.r), "+v"(d.e), "+v"(d.k), "+v"(d.a), "+v"(d.b),
                   "+v"(d.vv));
  };

  float sa;              // sa_t = S_{t-1}.a_t, ready at body t entry
  float ybatch = 0.0f;   // reduced y's; lane cg holds step (8m+cg)

  auto body = [&](Buf& cur, Buf& nx1, Buf& nx2, int t) {
    // stage(t+2) (issued at body t-6) resident: bodies t-5..t-1 issued
    // 10 loads + <=1 flush store newer -> vmcnt(10).
    asm volatile("s_waitcnt vmcnt(10)" ::: "memory");
    lds_read(nx2, (t + 2) & 7);
    wait_nx1(nx1);

    // ---- inline exp on nx1.e (consumed NEXT body as cur.e; off-chain) ----
    nx1.e[0] = __expf(nx1.e[0]);
    nx1.e[1] = __expf(nx1.e[1]);
    nx1.e[2] = __expf(nx1.e[2]);
    nx1.e[3] = __expf(nx1.e[3]);

    // ---- state update for step t (sa ready since last body) ----
    const float vv = cur.vv;
    s[0] = fmaf(cur.e[0], s[0], fmaf(sa, cur.b[0], vv * cur.k[0]));
    s[1] = fmaf(cur.e[1], s[1], fmaf(sa, cur.b[1], vv * cur.k[1]));
    s[2] = fmaf(cur.e[2], s[2], fmaf(sa, cur.b[2], vv * cur.k[2]));
    s[3] = fmaf(cur.e[3], s[3], fmaf(sa, cur.b[3], vv * cur.k[3]));

    // ---- both dots (partials) ----
    float qd = dot4(s, nx1.a);   // -> sa_{t+1}
    float yd = dot4(s, cur.r);   // -> y_t

    stage((t + 8) & (T_LEN - 1), t & 7);

    // ---- interleaved dual reduction ----
    duo_reduce(qd, yd);
    sa = qd;

    // ---- y batching: lane (t&7) keeps y_t; flush every 8 bodies ----
    ybatch = (cg == (t & 7)) ? yd : ybatch;
    if ((t & 7) == 7) {          // compile-time after unroll-8
      if (cg < 8) {              // 32 lanes: 8 t-slots x 4 rows
        int voff = (t - 7) * (HD * 4) + ybo;
        asm volatile("global_store_dword %0, %1, %2"
                     :: "v"(voff), "v"(ybatch), "s"(X) : "memory");
      }
    }
  };

  // Prologue: fill ring (issue order = count order).
  for (int i = 0; i < 8; ++i) {
    stage(i, i);
    __builtin_amdgcn_sched_barrier(0);
  }
  // Slots 0,1 done: stages 2..7 = 12 newer load ops.
  asm volatile("s_waitcnt vmcnt(12)" ::: "memory");

  Buf B0, B1, B2, B3;
  lds_read(B0, 0);
  lds_read(B1, 1);
  asm volatile("s_waitcnt lgkmcnt(0)"
               : "+v"(B0.r), "+v"(B0.e), "+v"(B0.k), "+v"(B0.a), "+v"(B0.b),
                 "+v"(B0.vv), "+v"(B1.a));

  // B0 is consumed as cur at body 0: exp its e now (B1+ handled in-body).
  B0.e[0] = __expf(B0.e[0]);
  B0.e[1] = __expf(B0.e[1]);
  B0.e[2] = __expf(B0.e[2]);
  B0.e[3] = __expf(B0.e[3]);

  // sa_0 = S_init . a_0 (prologue pays one serial reduce)
  sa = row16_reduce(dot4(s, B0.a));

  for (int t = 0; t < T_LEN; t += 8) {
    body(B0, B1, B2, t);
    body(B1, B2, B3, t + 1);
    body(B2, B3, B0, t + 2);
    body(B3, B0, B1, t + 3);
    body(B0, B1, B2, t + 4);
    body(B1, B2, B3, t + 5);
    body(B2, B3, B0, t + 6);
    body(B3, B0, B1, t + 7);
  }
  // Loop ends at t=2047 with (t&7)==7 -> final flush covered steps 2040..2047.

  *(f32x4*)(SOUT + (size_t)h * DD * DD + row * DD + c0) = s;
}

extern "C" void kernel_launch(void* const* d_in, const int* in_sizes, int n_in,
                              void* d_out, int out_size, void* d_ws, size_t ws_size,
                              hipStream_t stream) {
  // setup_inputs order: seq_length, r, w, k, v, a, b, state2
  const float* r  = (const float*)d_in[1];
  const float* w  = (const float*)d_in[2];
  const float* k  = (const float*)d_in[3];
  const float* v  = (const float*)d_in[4];
  const float* a  = (const float*)d_in[5];
  const float* b  = (const float*)d_in[6];
  const float* s0 = (const float*)d_in[7];

  float* x    = (float*)d_out;                     // (T, H, 1, D)
  float* sout = x + (size_t)T_LEN * HD;            // (H, D, D)

  (void)ws_size; (void)in_sizes; (void)n_in; (void)d_ws;

  hipLaunchKernelGGL(wkv7_scan, dim3(1024), dim3(64), 0, stream,
                     r, w, k, v, a, b, s0, x, sout);
}

// Round 21
// 242.913 us; speedup vs baseline: 1.1351x; 1.1351x over previous
//
#include <hip/hip_runtime.h>

// WKV7 (RWKV-7) forward scan. T=2048, H=64, D=64.
// R21 = R19 verbatim (best verified: 243us bench / 276us scan dispatch).
// R20's inline-exp regressed (+40 cyc/step trans/VALU issue > 15us dispatch
// saving) -> exp pre-pass restored.
// Structure: 1024 blocks x 64 thr (1 wave/block, 4 waves/CU), width-16 2-op
// global_load_lds staging (lane-grouped sources: op1=R|EW|K|A, op2=B|V),
// 8-slot 2KB LDS ring, 3-deep register buffers, counted vmcnt(10)/lgkmcnt(6),
// dual interleaved DPP reduce (s_nop 1 entry-hazard guard), batched y-store
// (lane cg<8 holds step t0+cg; 1 scatter store per 8 steps).
// Fitted model: step time ~ per-CU DS/TA service wall: 4 waves x (6 DS reads
// + 2 DMA + 1/8 store) ~= 33 wave-ops x ~10-12 cyc ~= 323 cyc measured.
// HBM 6%, VALU 44% -- binder is LDS op-granularity throughput (measured
// ds_read_b128 ~12 cyc). All structural alternatives tested worse:
// R11 (reg-direct), R12 (shared staging+barriers), R13/R15 (TLP=2),
// R18 (C=8), R20 (in-scan exp).

typedef float f32x4 __attribute__((ext_vector_type(4)));

constexpr int T_LEN = 2048;
constexpr int DD    = 64;
constexpr int HD    = 64 * 64;   // 4096

#define AS1 __attribute__((address_space(1)))
#define AS3 __attribute__((address_space(3)))

struct Buf { f32x4 r, e, k, a, b; float vv; };

__global__ __launch_bounds__(256)
void exp_kernel(const float4* __restrict__ w, float4* __restrict__ ew, int n4) {
  int i = blockIdx.x * blockDim.x + threadIdx.x;
  int stride = gridDim.x * blockDim.x;
  for (; i < n4; i += stride) {
    float4 x = w[i];
    float4 o;
    o.x = __expf(x.x); o.y = __expf(x.y); o.z = __expf(x.z); o.w = __expf(x.w);
    ew[i] = o;
  }
}

template<int CTRL>
__device__ __forceinline__ float dpp_add(float x) {
  int y = __builtin_amdgcn_update_dpp(0, __float_as_int(x), CTRL, 0xf, 0xf, true);
  return x + __int_as_float(y);
}

// Serial 16-lane reduce (prologue only).
__device__ __forceinline__ float row16_reduce(float x) {
  x = dpp_add<0xB1>(x);    // quad_perm [1,0,3,2]
  x = dpp_add<0x4E>(x);    // quad_perm [2,3,0,1]
  x = dpp_add<0x141>(x);   // row_half_mirror
  x = dpp_add<0x140>(x);   // row_mirror
  return x;
}

// Two interleaved row-of-16 reductions; s_nop 1 covers the entry
// VALU-write -> DPP-read hazard (R8 lesson).
__device__ __forceinline__ void duo_reduce(float& a, float& b) {
  float t0, t1;
  asm volatile(
    "s_nop 1\n\t"
    "v_mov_b32_dpp %2, %0 quad_perm:[1,0,3,2] row_mask:0xf bank_mask:0xf\n\t"
    "v_mov_b32_dpp %3, %1 quad_perm:[1,0,3,2] row_mask:0xf bank_mask:0xf\n\t"
    "s_nop 0\n\t"
    "v_add_f32 %0, %0, %2\n\t"
    "v_add_f32 %1, %1, %3\n\t"
    "s_nop 0\n\t"
    "v_mov_b32_dpp %2, %0 quad_perm:[2,3,0,1] row_mask:0xf bank_mask:0xf\n\t"
    "v_mov_b32_dpp %3, %1 quad_perm:[2,3,0,1] row_mask:0xf bank_mask:0xf\n\t"
    "s_nop 0\n\t"
    "v_add_f32 %0, %0, %2\n\t"
    "v_add_f32 %1, %1, %3\n\t"
    "s_nop 0\n\t"
    "v_mov_b32_dpp %2, %0 row_half_mirror row_mask:0xf bank_mask:0xf\n\t"
    "v_mov_b32_dpp %3, %1 row_half_mirror row_mask:0xf bank_mask:0xf\n\t"
    "s_nop 0\n\t"
    "v_add_f32 %0, %0, %2\n\t"
    "v_add_f32 %1, %1, %3\n\t"
    "s_nop 0\n\t"
    "v_mov_b32_dpp %2, %0 row_mirror row_mask:0xf bank_mask:0xf\n\t"
    "v_mov_b32_dpp %3, %1 row_mirror row_mask:0xf bank_mask:0xf\n\t"
    "s_nop 0\n\t"
    "v_add_f32 %0, %0, %2\n\t"
    "v_add_f32 %1, %1, %3"
    : "+v"(a), "+v"(b), "=&v"(t0), "=&v"(t1));
}

__device__ __forceinline__ float dot4(const f32x4& x, const f32x4& y) {
  return fmaf(x[3], y[3], fmaf(x[2], y[2], fmaf(x[1], y[1], x[0] * y[0])));
}

__device__ __forceinline__ void gload_lds16(const float* g, const float* l) {
  __builtin_amdgcn_global_load_lds((const AS1 unsigned*)g, (AS3 unsigned*)l, 16, 0, 0);
}

__global__ __launch_bounds__(64, 1)
void wkv7_scan(const float* __restrict__ R, const float* __restrict__ EW,
               const float* __restrict__ K, const float* __restrict__ V,
               const float* __restrict__ A, const float* __restrict__ B,
               const float* __restrict__ S0, float* __restrict__ X,
               float* __restrict__ SOUT)
{
  // 8 slots x 512 floats (2KB: R|EW|K|A | B|V|pad) = 16 KB
  __shared__ float smem[4096];

  const int blk = blockIdx.x;          // 0..1023
  const int xcd = blk & 7;
  const int m   = blk >> 3;            // 0..127
  const int h   = xcd * 8 + (m & 7);   // head 0..63
  const int br  = m >> 3;              // row block 0..15

  const int lane = threadIdx.x;        // 0..63
  const int cg   = lane & 15;          // cols [cg*4, cg*4+4)
  const int rl   = lane >> 4;          // local row 0..3
  const int row  = br * 4 + rl;        // 0..63
  const int c0   = cg * 4;

  // Staging sources (width-16 lane grouping):
  const int g1   = lane >> 4;          // source-array group 0..3
  const int sub16 = lane & 15;         // 16B chunk within the 256B array
  const float* base1 = (g1 == 0) ? R : (g1 == 1) ? EW : (g1 == 2) ? K : A;
  const float* base2 = (g1 == 0) ? B : V;   // g1>=1 dups V into pad
  const float* p1 = base1 + h * DD + sub16 * 4;
  const float* p2 = base2 + h * DD + sub16 * 4;

  const unsigned lb  = (unsigned)(uintptr_t)(AS3 float*)&smem[0];
  const unsigned vab = lb + (unsigned)(cg * 16);   // vector-read base
  const unsigned vvb = lb + (unsigned)(row * 4);   // v-read base (+1280 imm)

  // y batched store: lane cg<8 stores step (t0+cg) of its row.
  const int ybo = (cg * HD + h * DD + row) * 4;

  f32x4 s;
  {
    const f32x4* sp = (const f32x4*)(S0 + (size_t)h * DD * DD + row * DD + c0);
    s = *sp;
  }

  auto stage = [&](int tt, int slot) {
    const size_t o = (size_t)tt * HD;
    const float* l = &smem[slot * 512];
    gload_lds16(p1 + o, l);          // R|EW|K|A -> slot[0..1024)B
    gload_lds16(p2 + o, l + 256);    // B|V|pad  -> slot[1024..2048)B
  };

  auto lds_read = [&](Buf& d, int slot) {
    unsigned va = vab + (unsigned)(slot * 2048);
    unsigned vv = vvb + (unsigned)(slot * 2048);
    asm volatile(
      "ds_read_b128 %0, %6\n\t"
      "ds_read_b128 %1, %6 offset:256\n\t"
      "ds_read_b128 %2, %6 offset:512\n\t"
      "ds_read_b128 %3, %6 offset:768\n\t"
      "ds_read_b128 %4, %6 offset:1024\n\t"
      "ds_read_b32  %5, %7 offset:1280"
      : "=&v"(d.r), "=&v"(d.e), "=&v"(d.k), "=&v"(d.a), "=&v"(d.b), "=&v"(d.vv)
      : "v"(va), "v"(vv) : "memory");
  };

  auto wait_nx1 = [&](Buf& d) {
    asm volatile("s_waitcnt lgkmcnt(6)"
                 : "+v"(d.r), "+v"(d.e), "+v"(d.k), "+v"(d.a), "+v"(d.b),
                   "+v"(d.vv));
  };

  float sa;              // sa_t = S_{t-1}.a_t, ready at body t entry
  float ybatch = 0.0f;   // reduced y's; lane cg holds step (8m+cg)

  auto body = [&](Buf& cur, Buf& nx1, Buf& nx2, int t) {
    // stage(t+2) (issued at body t-6) resident: bodies t-5..t-1 issued
    // 10 loads + <=1 flush store newer -> vmcnt(10).
    asm volatile("s_waitcnt vmcnt(10)" ::: "memory");
    lds_read(nx2, (t + 2) & 7);
    wait_nx1(nx1);

    // ---- state update for step t (sa ready since last body) ----
    const float vv = cur.vv;
    s[0] = fmaf(cur.e[0], s[0], fmaf(sa, cur.b[0], vv * cur.k[0]));
    s[1] = fmaf(cur.e[1], s[1], fmaf(sa, cur.b[1], vv * cur.k[1]));
    s[2] = fmaf(cur.e[2], s[2], fmaf(sa, cur.b[2], vv * cur.k[2]));
    s[3] = fmaf(cur.e[3], s[3], fmaf(sa, cur.b[3], vv * cur.k[3]));

    // ---- both dots (partials) ----
    float qd = dot4(s, nx1.a);   // -> sa_{t+1}
    float yd = dot4(s, cur.r);   // -> y_t

    stage((t + 8) & (T_LEN - 1), t & 7);

    // ---- interleaved dual reduction ----
    duo_reduce(qd, yd);
    sa = qd;

    // ---- y batching: lane (t&7) keeps y_t; flush every 8 bodies ----
    ybatch = (cg == (t & 7)) ? yd : ybatch;
    if ((t & 7) == 7) {          // compile-time after unroll-8
      if (cg < 8) {              // 32 lanes: 8 t-slots x 4 rows
        int voff = (t - 7) * (HD * 4) + ybo;
        asm volatile("global_store_dword %0, %1, %2"
                     :: "v"(voff), "v"(ybatch), "s"(X) : "memory");
      }
    }
  };

  // Prologue: fill ring (issue order = count order).
  for (int i = 0; i < 8; ++i) {
    stage(i, i);
    __builtin_amdgcn_sched_barrier(0);
  }
  // Slots 0,1 done: stages 2..7 = 12 newer load ops.
  asm volatile("s_waitcnt vmcnt(12)" ::: "memory");

  Buf B0, B1, B2, B3;
  lds_read(B0, 0);
  lds_read(B1, 1);
  asm volatile("s_waitcnt lgkmcnt(0)"
               : "+v"(B0.r), "+v"(B0.e), "+v"(B0.k), "+v"(B0.a), "+v"(B0.b),
                 "+v"(B0.vv), "+v"(B1.a));

  // sa_0 = S_init . a_0 (prologue pays one serial reduce)
  sa = row16_reduce(dot4(s, B0.a));

  for (int t = 0; t < T_LEN; t += 8) {
    body(B0, B1, B2, t);
    body(B1, B2, B3, t + 1);
    body(B2, B3, B0, t + 2);
    body(B3, B0, B1, t + 3);
    body(B0, B1, B2, t + 4);
    body(B1, B2, B3, t + 5);
    body(B2, B3, B0, t + 6);
    body(B3, B0, B1, t + 7);
  }
  // Loop ends at t=2047 with (t&7)==7 -> final flush covered steps 2040..2047.

  *(f32x4*)(SOUT + (size_t)h * DD * DD + row * DD + c0) = s;
}

extern "C" void kernel_launch(void* const* d_in, const int* in_sizes, int n_in,
                              void* d_out, int out_size, void* d_ws, size_t ws_size,
                              hipStream_t stream) {
  // setup_inputs order: seq_length, r, w, k, v, a, b, state2
  const float* r  = (const float*)d_in[1];
  const float* w  = (const float*)d_in[2];
  const float* k  = (const float*)d_in[3];
  const float* v  = (const float*)d_in[4];
  const float* a  = (const float*)d_in[5];
  const float* b  = (const float*)d_in[6];
  const float* s0 = (const float*)d_in[7];

  float* x    = (float*)d_out;                     // (T, H, 1, D)
  float* sout = x + (size_t)T_LEN * HD;            // (H, D, D)

  float* ew = (float*)d_ws;
  (void)ws_size; (void)in_sizes; (void)n_in;

  int n4 = T_LEN * HD / 4;
  hipLaunchKernelGGL(exp_kernel, dim3(1024), dim3(256), 0, stream,
                     (const float4*)w, (float4*)ew, n4);
  hipLaunchKernelGGL(wkv7_scan, dim3(1024), dim3(64), 0, stream,
                     r, ew, k, v, a, b, s0, x, sout);
}